// Round 1
// baseline (231.978 us; speedup 1.0000x reference)
//
#include <hip/hip_runtime.h>
#include <stdint.h>

#define B_  16
#define C_  512
#define C1_ 256
#define HW_ 4096

using bf16x8 = __attribute__((ext_vector_type(8))) short;
using f32x4  = __attribute__((ext_vector_type(4))) float;

__device__ __forceinline__ unsigned short f2bf(float f) {
  union { float f; unsigned int u; } v; v.f = f;
  unsigned int r = v.u + 0x7fffu + ((v.u >> 16) & 1u);
  return (unsigned short)(r >> 16);
}

__device__ __forceinline__ void gload_lds16(const void* g, void* l) {
  __builtin_amdgcn_global_load_lds(
      (const __attribute__((address_space(1))) void*)g,
      (__attribute__((address_space(3))) void*)l, 16, 0, 0);
}

// ---------------------------------------------------------------------------
// K1: x (f32) -> Xbf (bf16), plus per-row sums s[b*C_+c] = sum_n x[b,c,n]
// grid: 8192 blocks (one per (b,c) row), 256 threads
__global__ __launch_bounds__(256) void k_convert(const float* __restrict__ x,
                                                 short* __restrict__ Xbf,
                                                 float* __restrict__ s) {
  const int row = blockIdx.x;
  const int t = threadIdx.x;
  const float4* xr = (const float4*)(x + (size_t)row * HW_);
  short4* xo = (short4*)(Xbf + (size_t)row * HW_);
  float sum = 0.f;
#pragma unroll
  for (int i = 0; i < 4; ++i) {
    float4 v = xr[i * 256 + t];
    sum += (v.x + v.y) + (v.z + v.w);
    short4 o;
    o.x = (short)f2bf(v.x); o.y = (short)f2bf(v.y);
    o.z = (short)f2bf(v.z); o.w = (short)f2bf(v.w);
    xo[i * 256 + t] = o;
  }
#pragma unroll
  for (int off = 1; off < 64; off <<= 1) sum += __shfl_xor(sum, off);
  __shared__ float red[4];
  if ((t & 63) == 0) red[t >> 6] = sum;
  __syncthreads();
  if (t == 0) s[row] = (red[0] + red[1]) + (red[2] + red[3]);
}

// ---------------------------------------------------------------------------
// K1b: conv_w (256x512 f32) -> Wbf4 (256x2048 bf16, duplicated 4x along K for
// the K-split-concatenated Gram layout). grid: 256 blocks, 256 threads.
__global__ __launch_bounds__(256) void k_wconv(const float* __restrict__ W,
                                               short* __restrict__ Wbf4) {
  const int q = blockIdx.x;
  const int t = threadIdx.x;
  float2 v = ((const float2*)(W + (size_t)q * 512))[t];
  short2 o; o.x = (short)f2bf(v.x); o.y = (short)f2bf(v.y);
  short2* dst = (short2*)(Wbf4 + (size_t)q * 2048);
#pragma unroll
  for (int ks = 0; ks < 4; ++ks) dst[ks * 256 + t] = o;
}

// ---------------------------------------------------------------------------
// K2: per-batch Gram, split-K by 4. Gc[b][i][ks*512+j] = sum_{n in chunk ks}
// X[i,n]*X[j,n], stored bf16. NT GEMM 128x128 tile, BK=32, m97 structure.
// grid: dim3(16 tiles, 4 ks, 16 b), 256 threads (4 waves, 2x2 of 64x64).
__global__ __launch_bounds__(256, 2) void k_gram(const short* __restrict__ Xbf,
                                                 short* __restrict__ Gc) {
  __shared__ short As[128 * 32];
  __shared__ short Bs[128 * 32];
  const int t = threadIdx.x;
  const int tm = blockIdx.x >> 2, tn = blockIdx.x & 3;
  const int ks = blockIdx.y, b = blockIdx.z;
  const short* Ab = Xbf + ((size_t)b * C_ + tm * 128) * HW_;
  const short* Bb = Xbf + ((size_t)b * C_ + tn * 128) * HW_;
  const int lane = t & 63, w = t >> 6;
  const int wr = w >> 1, wc = w & 1;
  const int fr = lane & 15, fk = (lane >> 4) * 8;
  const int row_st = t >> 2;          // 0..63
  const int k_st = (t & 3) * 8;       // 0,8,16,24
  const int kbase = ks * 1024;
  f32x4 acc[4][4] = {};
  for (int kk = 0; kk < 32; ++kk) {
    const int k0 = kbase + kk * 32 + k_st;
    gload_lds16(Ab + (size_t)row_st * HW_ + k0, &As[t * 8]);
    gload_lds16(Ab + (size_t)(row_st + 64) * HW_ + k0, &As[2048 + t * 8]);
    gload_lds16(Bb + (size_t)row_st * HW_ + k0, &Bs[t * 8]);
    gload_lds16(Bb + (size_t)(row_st + 64) * HW_ + k0, &Bs[2048 + t * 8]);
    __syncthreads();
    bf16x8 a[4], bv[4];
#pragma unroll
    for (int m = 0; m < 4; ++m)
      a[m] = *(const bf16x8*)&As[(wr * 64 + m * 16 + fr) * 32 + fk];
#pragma unroll
    for (int n = 0; n < 4; ++n)
      bv[n] = *(const bf16x8*)&Bs[(wc * 64 + n * 16 + fr) * 32 + fk];
#pragma unroll
    for (int m = 0; m < 4; ++m)
#pragma unroll
      for (int n = 0; n < 4; ++n)
        acc[m][n] = __builtin_amdgcn_mfma_f32_16x16x32_bf16(a[m], bv[n], acc[m][n], 0, 0, 0);
    __syncthreads();
  }
  const int r_base = tm * 128 + wr * 64;
  const int c_base = tn * 128 + wc * 64;
#pragma unroll
  for (int m = 0; m < 4; ++m)
#pragma unroll
    for (int n = 0; n < 4; ++n) {
      const int rr = r_base + m * 16 + (lane >> 4) * 4;
      const int cc = c_base + n * 16 + (lane & 15);
#pragma unroll
      for (int r = 0; r < 4; ++r)
        Gc[((size_t)b * C_ + rr + r) * 2048 + ks * 512 + cc] = (short)f2bf(acc[m][n][r]);
    }
}

// ---------------------------------------------------------------------------
// K3: E[b][q][c] = (sum_K Wbf4[q][K]*Gc[b][c][K] + conv_b[q]*s[b][c]) / 64.
// NT GEMM M=256 N=512 K=2048, 128x128 tiles. grid: dim3(8,1,16), 256 thr.
__global__ __launch_bounds__(256, 2) void k_energy(const short* __restrict__ Wbf4,
                                                   const short* __restrict__ Gc,
                                                   const float* __restrict__ convb,
                                                   const float* __restrict__ s,
                                                   float* __restrict__ E) {
  __shared__ short As[128 * 32];
  __shared__ short Bs[128 * 32];
  const int t = threadIdx.x;
  const int qt = blockIdx.x >> 2, ct = blockIdx.x & 3;
  const int b = blockIdx.z;
  const short* Ab = Wbf4 + (size_t)(qt * 128) * 2048;
  const short* Bb = Gc + ((size_t)b * C_ + ct * 128) * 2048;
  const int lane = t & 63, w = t >> 6;
  const int wr = w >> 1, wc = w & 1;
  const int fr = lane & 15, fk = (lane >> 4) * 8;
  const int row_st = t >> 2;
  const int k_st = (t & 3) * 8;
  f32x4 acc[4][4] = {};
  for (int kk = 0; kk < 64; ++kk) {
    const int k0 = kk * 32 + k_st;
    gload_lds16(Ab + (size_t)row_st * 2048 + k0, &As[t * 8]);
    gload_lds16(Ab + (size_t)(row_st + 64) * 2048 + k0, &As[2048 + t * 8]);
    gload_lds16(Bb + (size_t)row_st * 2048 + k0, &Bs[t * 8]);
    gload_lds16(Bb + (size_t)(row_st + 64) * 2048 + k0, &Bs[2048 + t * 8]);
    __syncthreads();
    bf16x8 a[4], bv[4];
#pragma unroll
    for (int m = 0; m < 4; ++m)
      a[m] = *(const bf16x8*)&As[(wr * 64 + m * 16 + fr) * 32 + fk];
#pragma unroll
    for (int n = 0; n < 4; ++n)
      bv[n] = *(const bf16x8*)&Bs[(wc * 64 + n * 16 + fr) * 32 + fk];
#pragma unroll
    for (int m = 0; m < 4; ++m)
#pragma unroll
      for (int n = 0; n < 4; ++n)
        acc[m][n] = __builtin_amdgcn_mfma_f32_16x16x32_bf16(a[m], bv[n], acc[m][n], 0, 0, 0);
    __syncthreads();
  }
  const int q_base = qt * 128 + wr * 64;
  const int c_base = ct * 128 + wc * 64;
#pragma unroll
  for (int m = 0; m < 4; ++m)
#pragma unroll
    for (int n = 0; n < 4; ++n) {
      const int q = q_base + m * 16 + (lane >> 4) * 4;
      const int c = c_base + n * 16 + (lane & 15);
      const float sv = s[b * C_ + c];
#pragma unroll
      for (int r = 0; r < 4; ++r)
        E[((size_t)b * C1_ + q + r) * C_ + c] =
            (acc[m][n][r] + convb[q + r] * sv) * 0.015625f;
    }
}

// ---------------------------------------------------------------------------
// K4: per (b,q) row: A = softmax(E row), Mb = gamma*A + W[q]  (bf16).
// grid: 4096 blocks, 128 threads (each thread owns 4 consecutive c).
__global__ __launch_bounds__(128) void k_softmax(const float* __restrict__ E,
                                                 const float* __restrict__ W,
                                                 const float* __restrict__ gamma,
                                                 short* __restrict__ Mb) {
  const int bq = blockIdx.x;
  const int t = threadIdx.x;
  const float g = gamma[0];
  const float4 v = ((const float4*)(E + (size_t)bq * C_))[t];
  float mx = fmaxf(fmaxf(v.x, v.y), fmaxf(v.z, v.w));
#pragma unroll
  for (int off = 1; off < 64; off <<= 1) mx = fmaxf(mx, __shfl_xor(mx, off));
  __shared__ float red[2];
  if ((t & 63) == 0) red[t >> 6] = mx;
  __syncthreads();
  mx = fmaxf(red[0], red[1]);
  const float e0 = __expf(v.x - mx), e1 = __expf(v.y - mx);
  const float e2 = __expf(v.z - mx), e3 = __expf(v.w - mx);
  float sum = (e0 + e1) + (e2 + e3);
#pragma unroll
  for (int off = 1; off < 64; off <<= 1) sum += __shfl_xor(sum, off);
  __shared__ float red2[2];
  if ((t & 63) == 0) red2[t >> 6] = sum;
  __syncthreads();
  const float inv = 1.0f / (red2[0] + red2[1]);
  const int q = bq & 255;
  const float4 wv = ((const float4*)(W + (size_t)q * C_))[t];
  short4 o;
  o.x = (short)f2bf(g * e0 * inv + wv.x);
  o.y = (short)f2bf(g * e1 * inv + wv.y);
  o.z = (short)f2bf(g * e2 * inv + wv.z);
  o.w = (short)f2bf(g * e3 * inv + wv.w);
  ((short4*)(Mb + (size_t)bq * C_))[t] = o;
}

// ---------------------------------------------------------------------------
// K5: out[b][o][n] = sum_c Mb[b][o][c] * X[b][c][n] + conv_b[o].
// NN GEMM M=256 N=4096 K=512; B-tile (X) transposed through LDS (pad 40 so
// ds_read_b128 stays 16B-aligned). grid: dim3(64, 16), 256 threads.
__global__ __launch_bounds__(256, 2) void k_out(const short* __restrict__ Mb,
                                                const short* __restrict__ Xbf,
                                                const float* __restrict__ convb,
                                                float* __restrict__ out) {
  __shared__ short As[128 * 32];
  __shared__ short Bt[128 * 40];
  const int t = threadIdx.x;
  const int ot = blockIdx.x >> 5, nt = blockIdx.x & 31;
  const int b = blockIdx.y;
  const int n0 = nt * 128;
  const int lane = t & 63, w = t >> 6;
  const int wr = w >> 1, wc = w & 1;
  const int fr = lane & 15, fk = (lane >> 4) * 8;
  const int row_st = t >> 2, k_st = (t & 3) * 8;
  const int krow = t >> 4, ncol = (t & 15) * 8;
  const short* Abase = Mb + ((size_t)b * C1_ + ot * 128) * C_;
  const short* Xb = Xbf + (size_t)b * C_ * HW_;
  f32x4 acc[4][4] = {};
  for (int kk = 0; kk < 16; ++kk) {
    const int k0 = kk * 32;
    gload_lds16(Abase + (size_t)row_st * C_ + k0 + k_st, &As[t * 8]);
    gload_lds16(Abase + (size_t)(row_st + 64) * C_ + k0 + k_st, &As[2048 + t * 8]);
    const bf16x8 v0 = *(const bf16x8*)&Xb[(size_t)(k0 + krow) * HW_ + n0 + ncol];
    const bf16x8 v1 = *(const bf16x8*)&Xb[(size_t)(k0 + 16 + krow) * HW_ + n0 + ncol];
#pragma unroll
    for (int i = 0; i < 8; ++i) Bt[(ncol + i) * 40 + krow] = v0[i];
#pragma unroll
    for (int i = 0; i < 8; ++i) Bt[(ncol + i) * 40 + 16 + krow] = v1[i];
    __syncthreads();
    bf16x8 a[4], bv[4];
#pragma unroll
    for (int m = 0; m < 4; ++m)
      a[m] = *(const bf16x8*)&As[(wr * 64 + m * 16 + fr) * 32 + fk];
#pragma unroll
    for (int n = 0; n < 4; ++n)
      bv[n] = *(const bf16x8*)&Bt[(wc * 64 + n * 16 + fr) * 40 + fk];
#pragma unroll
    for (int m = 0; m < 4; ++m)
#pragma unroll
      for (int n = 0; n < 4; ++n)
        acc[m][n] = __builtin_amdgcn_mfma_f32_16x16x32_bf16(a[m], bv[n], acc[m][n], 0, 0, 0);
    __syncthreads();
  }
  const int o_base = ot * 128 + wr * 64;
  const int nb = n0 + wc * 64;
#pragma unroll
  for (int m = 0; m < 4; ++m)
#pragma unroll
    for (int n = 0; n < 4; ++n) {
      const int oo = o_base + m * 16 + (lane >> 4) * 4;
      const int nn = nb + n * 16 + (lane & 15);
#pragma unroll
      for (int r = 0; r < 4; ++r)
        out[((size_t)b * C1_ + oo + r) * HW_ + nn] = acc[m][n][r] + convb[oo + r];
    }
}

// ---------------------------------------------------------------------------
extern "C" void kernel_launch(void* const* d_in, const int* in_sizes, int n_in,
                              void* d_out, int out_size, void* d_ws, size_t ws_size,
                              hipStream_t stream) {
  const float* x      = (const float*)d_in[0];
  const float* conv_w = (const float*)d_in[1];
  const float* conv_b = (const float*)d_in[2];
  const float* gamma  = (const float*)d_in[3];
  float* out = (float*)d_out;

  char* ws = (char*)d_ws;
  short* Xbf  = (short*)(ws);                 //  67,108,864 B : bf16 [16][512][4096]
  short* Gc   = (short*)(ws + 67108864);      //  33,554,432 B : bf16 [16][512][2048]
  short* Wbf4 = (short*)(ws + 100663296);     //   1,048,576 B : bf16 [256][2048]
  float* s    = (float*)(ws + 101711872);     //      32,768 B : f32  [16][512]
  float* E    = (float*)(ws + 101744640);     //   8,388,608 B : f32  [16][256][512]
  short* Mb   = (short*)(ws + 110133248);     //   4,194,304 B : bf16 [16][256][512]

  k_convert<<<8192, 256, 0, stream>>>(x, Xbf, s);
  k_wconv<<<256, 256, 0, stream>>>(conv_w, Wbf4);
  k_gram<<<dim3(16, 4, 16), 256, 0, stream>>>(Xbf, Gc);
  k_energy<<<dim3(8, 1, 16), 256, 0, stream>>>(Wbf4, Gc, conv_b, s, E);
  k_softmax<<<4096, 128, 0, stream>>>(E, conv_w, gamma, Mb);
  k_out<<<dim3(64, 16), 256, 0, stream>>>(Mb, Xbf, conv_b, out);
}

// Round 2
// 173.672 us; speedup vs baseline: 1.3357x; 1.3357x over previous
//
#include <hip/hip_runtime.h>
#include <stdint.h>

#define B_  16
#define C_  512
#define C1_ 256
#define HW_ 4096

using bf16x8 = __attribute__((ext_vector_type(8))) short;
using f32x4  = __attribute__((ext_vector_type(4))) float;

__device__ __forceinline__ short f2bf(float f) {
  union { float f; unsigned int u; } v; v.f = f;
  unsigned int r = v.u + 0x7fffu + ((v.u >> 16) & 1u);
  return (short)(r >> 16);
}
__device__ __forceinline__ float bf2f(short s) {
  union { unsigned int u; float f; } v;
  v.u = ((unsigned int)(unsigned short)s) << 16;
  return v.f;
}

__device__ __forceinline__ void gload_lds16(const void* g, void* l) {
  __builtin_amdgcn_global_load_lds(
      (const __attribute__((address_space(1))) void*)g,
      (__attribute__((address_space(3))) void*)l, 16, 0, 0);
}

// ---------------------------------------------------------------------------
// K1: x f32 [b][c][hw] -> Xbf bf16 [b][c][hw]  AND  XbfT bf16 [b][hw][c].
// Tile 64c x 128hw per block. Transpose via LDS (scalar writes ~4-way
// conflicts, b128 reads — all hidden under HBM traffic).
// grid: dim3(HW_/128=32, C_/64=8, B_=16), 256 threads.
__global__ __launch_bounds__(256) void k_convert(const float* __restrict__ x,
                                                 short* __restrict__ Xbf,
                                                 short* __restrict__ XbfT) {
  __shared__ short T[128][72];   // [n][c] transposed tile, stride 72 (mult 8)
  const int n0 = blockIdx.x * 128, c0 = blockIdx.y * 64, b = blockIdx.z;
  const int t = threadIdx.x;
  const int i = t >> 2;          // 0..63  (c within tile)
  const int jc = t & 3;
  const float* xrow = x + ((size_t)(b * C_ + c0 + i)) * HW_ + n0;
  short* yrow = Xbf + ((size_t)(b * C_ + c0 + i)) * HW_ + n0;
#pragma unroll
  for (int l = 0; l < 8; ++l) {
    const int n = 4 * jc + 16 * l;
    const float4 v = *(const float4*)(xrow + n);
    short4 o;
    o.x = f2bf(v.x); o.y = f2bf(v.y); o.z = f2bf(v.z); o.w = f2bf(v.w);
    *(short4*)(yrow + n) = o;
    T[n + 0][i] = o.x; T[n + 1][i] = o.y;
    T[n + 2][i] = o.z; T[n + 3][i] = o.w;
  }
  __syncthreads();
  const int nr = t & 127, ch = (t >> 7) * 32;   // each thread: 32 c for one n
  short* orow = XbfT + ((size_t)b * HW_ + n0 + nr) * C_ + c0 + ch;
  const bf16x8 u0 = *(const bf16x8*)&T[nr][ch + 0];
  const bf16x8 u1 = *(const bf16x8*)&T[nr][ch + 8];
  const bf16x8 u2 = *(const bf16x8*)&T[nr][ch + 16];
  const bf16x8 u3 = *(const bf16x8*)&T[nr][ch + 24];
  *(bf16x8*)(orow + 0)  = u0;
  *(bf16x8*)(orow + 8)  = u1;
  *(bf16x8*)(orow + 16) = u2;
  *(bf16x8*)(orow + 24) = u3;
}

// ---------------------------------------------------------------------------
// K1b: conv_w f32 [256][512] -> Wbf bf16 [256][512].
__global__ __launch_bounds__(256) void k_wconv(const float* __restrict__ W,
                                               short* __restrict__ Wbf) {
  const int q = blockIdx.x, t = threadIdx.x;
  const float2 v = ((const float2*)(W + (size_t)q * C_))[t];
  short2 o; o.x = f2bf(v.x); o.y = f2bf(v.y);
  ((short2*)(Wbf + (size_t)q * C_))[t] = o;
}

// ---------------------------------------------------------------------------
// K2: Q[b][q][n] = sum_c W[q][c]*XbfT[b][n][c] + conv_b[q]  (bf16 out).
// NT GEMM M=256 N=4096 K=512, 128x128 tile, BK=32, m97 structure.
// grid: dim3(64, 16): x = nt*2+mt, y = b. 256 threads.
__global__ __launch_bounds__(256, 2) void k_q(const short* __restrict__ Wbf,
                                              const short* __restrict__ XbfT,
                                              const float* __restrict__ convb,
                                              short* __restrict__ Qbf) {
  __shared__ short As[128 * 32];
  __shared__ short Bs[128 * 32];
  const int t = threadIdx.x;
  const int mt = blockIdx.x & 1, nt = blockIdx.x >> 1, b = blockIdx.y;
  const short* Ab = Wbf + (size_t)(mt * 128) * C_;
  const short* Bb = XbfT + ((size_t)b * HW_ + nt * 128) * C_;
  const int lane = t & 63, w = t >> 6;
  const int wr = w >> 1, wc = w & 1;
  const int fr = lane & 15, fk = (lane >> 4) * 8;
  const int row_st = t >> 2, k_st = (t & 3) * 8;
  f32x4 acc[4][4] = {};
  for (int kk = 0; kk < 16; ++kk) {
    const int k0 = kk * 32 + k_st;
    gload_lds16(Ab + (size_t)row_st * C_ + k0, &As[t * 8]);
    gload_lds16(Ab + (size_t)(row_st + 64) * C_ + k0, &As[2048 + t * 8]);
    gload_lds16(Bb + (size_t)row_st * C_ + k0, &Bs[t * 8]);
    gload_lds16(Bb + (size_t)(row_st + 64) * C_ + k0, &Bs[2048 + t * 8]);
    __syncthreads();
    bf16x8 a[4], bv[4];
#pragma unroll
    for (int m = 0; m < 4; ++m)
      a[m] = *(const bf16x8*)&As[(wr * 64 + m * 16 + fr) * 32 + fk];
#pragma unroll
    for (int n = 0; n < 4; ++n)
      bv[n] = *(const bf16x8*)&Bs[(wc * 64 + n * 16 + fr) * 32 + fk];
#pragma unroll
    for (int m = 0; m < 4; ++m)
#pragma unroll
      for (int n = 0; n < 4; ++n)
        acc[m][n] = __builtin_amdgcn_mfma_f32_16x16x32_bf16(a[m], bv[n], acc[m][n], 0, 0, 0);
    __syncthreads();
  }
  const int q_base = mt * 128 + wr * 64;
  const int n_base = nt * 128 + wc * 64;
#pragma unroll
  for (int m = 0; m < 4; ++m)
#pragma unroll
    for (int n = 0; n < 4; ++n) {
      const int q = q_base + m * 16 + (lane >> 4) * 4;
      const int nn = n_base + n * 16 + (lane & 15);
#pragma unroll
      for (int r = 0; r < 4; ++r)
        Qbf[((size_t)b * C1_ + q + r) * HW_ + nn] = f2bf(acc[m][n][r] + convb[q + r]);
    }
}

// ---------------------------------------------------------------------------
// K3: Ep[ks][b][q][c] = sum_{hw in ks chunk} Q[b][q][hw]*X[b][c][hw]  (bf16,
// unscaled partial). Split-K x4. 128x128 tile, BK=32, K-chunk=1024.
// grid: dim3(16, 8, 4): x=b, y= ct*2+qt, z=ks. 256 threads.
__global__ __launch_bounds__(256, 2) void k_e(const short* __restrict__ Qbf,
                                              const short* __restrict__ Xbf,
                                              short* __restrict__ Ep) {
  __shared__ short As[128 * 32];
  __shared__ short Bs[128 * 32];
  const int t = threadIdx.x;
  const int b = blockIdx.x;
  const int qt = blockIdx.y & 1, ct = blockIdx.y >> 1;
  const int ks = blockIdx.z;
  const short* Ab = Qbf + ((size_t)b * C1_ + qt * 128) * HW_ + ks * 1024;
  const short* Bb = Xbf + ((size_t)b * C_ + ct * 128) * HW_ + ks * 1024;
  const int lane = t & 63, w = t >> 6;
  const int wr = w >> 1, wc = w & 1;
  const int fr = lane & 15, fk = (lane >> 4) * 8;
  const int row_st = t >> 2, k_st = (t & 3) * 8;
  f32x4 acc[4][4] = {};
  for (int kk = 0; kk < 32; ++kk) {
    const int k0 = kk * 32 + k_st;
    gload_lds16(Ab + (size_t)row_st * HW_ + k0, &As[t * 8]);
    gload_lds16(Ab + (size_t)(row_st + 64) * HW_ + k0, &As[2048 + t * 8]);
    gload_lds16(Bb + (size_t)row_st * HW_ + k0, &Bs[t * 8]);
    gload_lds16(Bb + (size_t)(row_st + 64) * HW_ + k0, &Bs[2048 + t * 8]);
    __syncthreads();
    bf16x8 a[4], bv[4];
#pragma unroll
    for (int m = 0; m < 4; ++m)
      a[m] = *(const bf16x8*)&As[(wr * 64 + m * 16 + fr) * 32 + fk];
#pragma unroll
    for (int n = 0; n < 4; ++n)
      bv[n] = *(const bf16x8*)&Bs[(wc * 64 + n * 16 + fr) * 32 + fk];
#pragma unroll
    for (int m = 0; m < 4; ++m)
#pragma unroll
      for (int n = 0; n < 4; ++n)
        acc[m][n] = __builtin_amdgcn_mfma_f32_16x16x32_bf16(a[m], bv[n], acc[m][n], 0, 0, 0);
    __syncthreads();
  }
  const int q_base = qt * 128 + wr * 64;
  const int c_base = ct * 128 + wc * 64;
#pragma unroll
  for (int m = 0; m < 4; ++m)
#pragma unroll
    for (int n = 0; n < 4; ++n) {
      const int q = q_base + m * 16 + (lane >> 4) * 4;
      const int c = c_base + n * 16 + (lane & 15);
#pragma unroll
      for (int r = 0; r < 4; ++r)
        Ep[(((size_t)ks * B_ + b) * C1_ + q + r) * C_ + c] = f2bf(acc[m][n][r]);
    }
}

// ---------------------------------------------------------------------------
// K4: per (b,q) row: E = (sum_ks Ep)/64; A = softmax(E); Mb = gamma*A + W[q].
// grid: 4096 blocks (b*256+q), 128 threads (4 consecutive c each).
__global__ __launch_bounds__(128) void k_softmax(const short* __restrict__ Ep,
                                                 const float* __restrict__ W,
                                                 const float* __restrict__ gamma,
                                                 short* __restrict__ Mb) {
  const int bq = blockIdx.x;
  const int b = bq >> 8, q = bq & 255;
  const int t = threadIdx.x;
  const float g = gamma[0];
  float e[4] = {0.f, 0.f, 0.f, 0.f};
#pragma unroll
  for (int ks = 0; ks < 4; ++ks) {
    const short4 v = *(const short4*)&Ep[(((size_t)ks * B_ + b) * C1_ + q) * C_ + t * 4];
    e[0] += bf2f(v.x); e[1] += bf2f(v.y); e[2] += bf2f(v.z); e[3] += bf2f(v.w);
  }
#pragma unroll
  for (int d = 0; d < 4; ++d) e[d] *= 0.015625f;
  float mx = fmaxf(fmaxf(e[0], e[1]), fmaxf(e[2], e[3]));
#pragma unroll
  for (int off = 1; off < 64; off <<= 1) mx = fmaxf(mx, __shfl_xor(mx, off));
  __shared__ float red[2];
  if ((t & 63) == 0) red[t >> 6] = mx;
  __syncthreads();
  mx = fmaxf(red[0], red[1]);
  const float e0 = __expf(e[0] - mx), e1 = __expf(e[1] - mx);
  const float e2 = __expf(e[2] - mx), e3 = __expf(e[3] - mx);
  float sum = (e0 + e1) + (e2 + e3);
#pragma unroll
  for (int off = 1; off < 64; off <<= 1) sum += __shfl_xor(sum, off);
  __shared__ float red2[2];
  if ((t & 63) == 0) red2[t >> 6] = sum;
  __syncthreads();
  const float inv = 1.0f / (red2[0] + red2[1]);
  const float4 wv = ((const float4*)(W + (size_t)q * C_))[t];
  short4 o;
  o.x = f2bf(g * e0 * inv + wv.x);
  o.y = f2bf(g * e1 * inv + wv.y);
  o.z = f2bf(g * e2 * inv + wv.z);
  o.w = f2bf(g * e3 * inv + wv.w);
  ((short4*)(Mb + (size_t)bq * C_))[t] = o;
}

// ---------------------------------------------------------------------------
// K5: out[b][o][n] = sum_c Mb[b][o][c]*XbfT[b][n][c] + conv_b[o]  (f32 out).
// Same NT structure as k_q. grid: dim3(64, 16), 256 threads.
__global__ __launch_bounds__(256, 2) void k_out(const short* __restrict__ Mb,
                                                const short* __restrict__ XbfT,
                                                const float* __restrict__ convb,
                                                float* __restrict__ out) {
  __shared__ short As[128 * 32];
  __shared__ short Bs[128 * 32];
  const int t = threadIdx.x;
  const int mt = blockIdx.x & 1, nt = blockIdx.x >> 1, b = blockIdx.y;
  const short* Ab = Mb + ((size_t)b * C1_ + mt * 128) * C_;
  const short* Bb = XbfT + ((size_t)b * HW_ + nt * 128) * C_;
  const int lane = t & 63, w = t >> 6;
  const int wr = w >> 1, wc = w & 1;
  const int fr = lane & 15, fk = (lane >> 4) * 8;
  const int row_st = t >> 2, k_st = (t & 3) * 8;
  f32x4 acc[4][4] = {};
  for (int kk = 0; kk < 16; ++kk) {
    const int k0 = kk * 32 + k_st;
    gload_lds16(Ab + (size_t)row_st * C_ + k0, &As[t * 8]);
    gload_lds16(Ab + (size_t)(row_st + 64) * C_ + k0, &As[2048 + t * 8]);
    gload_lds16(Bb + (size_t)row_st * C_ + k0, &Bs[t * 8]);
    gload_lds16(Bb + (size_t)(row_st + 64) * C_ + k0, &Bs[2048 + t * 8]);
    __syncthreads();
    bf16x8 a[4], bv[4];
#pragma unroll
    for (int m = 0; m < 4; ++m)
      a[m] = *(const bf16x8*)&As[(wr * 64 + m * 16 + fr) * 32 + fk];
#pragma unroll
    for (int n = 0; n < 4; ++n)
      bv[n] = *(const bf16x8*)&Bs[(wc * 64 + n * 16 + fr) * 32 + fk];
#pragma unroll
    for (int m = 0; m < 4; ++m)
#pragma unroll
      for (int n = 0; n < 4; ++n)
        acc[m][n] = __builtin_amdgcn_mfma_f32_16x16x32_bf16(a[m], bv[n], acc[m][n], 0, 0, 0);
    __syncthreads();
  }
  const int o_base = mt * 128 + wr * 64;
  const int n_base = nt * 128 + wc * 64;
#pragma unroll
  for (int m = 0; m < 4; ++m)
#pragma unroll
    for (int n = 0; n < 4; ++n) {
      const int oo = o_base + m * 16 + (lane >> 4) * 4;
      const int nn = n_base + n * 16 + (lane & 15);
#pragma unroll
      for (int r = 0; r < 4; ++r)
        out[((size_t)b * C1_ + oo + r) * HW_ + nn] = acc[m][n][r] + convb[oo + r];
    }
}

// ---------------------------------------------------------------------------
extern "C" void kernel_launch(void* const* d_in, const int* in_sizes, int n_in,
                              void* d_out, int out_size, void* d_ws, size_t ws_size,
                              hipStream_t stream) {
  const float* x      = (const float*)d_in[0];
  const float* conv_w = (const float*)d_in[1];
  const float* conv_b = (const float*)d_in[2];
  const float* gamma  = (const float*)d_in[3];
  float* out = (float*)d_out;

  char* ws = (char*)d_ws;
  short* Xbf  = (short*)(ws);                 //  67,108,864 B : bf16 [16][512][4096]
  short* XbfT = (short*)(ws + 67108864);      //  67,108,864 B : bf16 [16][4096][512]
  short* Qbf  = (short*)(ws + 134217728);     //  33,554,432 B : bf16 [16][256][4096]
  short* Mb   = (short*)(ws + 134217728);     //   (aliases Qbf; Qbf dead by then)
  short* Ep   = (short*)(ws + 167772160);     //  16,777,216 B : bf16 [4][16][256][512]
  short* Wbf  = (short*)(ws + 184549376);     //     262,144 B : bf16 [256][512]
  // total need: 184,811,520 B

  k_convert<<<dim3(32, 8, 16), 256, 0, stream>>>(x, Xbf, XbfT);
  k_wconv<<<256, 256, 0, stream>>>(conv_w, Wbf);
  k_q<<<dim3(64, 16), 256, 0, stream>>>(Wbf, XbfT, conv_b, Qbf);
  k_e<<<dim3(16, 8, 4), 256, 0, stream>>>(Qbf, Xbf, Ep);
  k_softmax<<<4096, 128, 0, stream>>>(Ep, conv_w, gamma, Mb);
  k_out<<<dim3(64, 16), 256, 0, stream>>>(Mb, XbfT, conv_b, out);
}

// Round 3
// 156.159 us; speedup vs baseline: 1.4855x; 1.1121x over previous
//
#include <hip/hip_runtime.h>
#include <stdint.h>

#define B_  16
#define C_  512
#define C1_ 256
#define HW_ 4096

using bf16x8 = __attribute__((ext_vector_type(8))) short;
using f32x4  = __attribute__((ext_vector_type(4))) float;

__device__ __forceinline__ short f2bf(float f) {
  union { float f; unsigned int u; } v; v.f = f;
  unsigned int r = v.u + 0x7fffu + ((v.u >> 16) & 1u);
  return (short)(r >> 16);
}
__device__ __forceinline__ float bf2f(short s) {
  union { unsigned int u; float f; } v;
  v.u = ((unsigned int)(unsigned short)s) << 16;
  return v.f;
}

__device__ __forceinline__ void gload_lds16(const void* g, void* l) {
  __builtin_amdgcn_global_load_lds(
      (const __attribute__((address_space(1))) void*)g,
      (__attribute__((address_space(3))) void*)l, 16, 0, 0);
}

// ---------------------------------------------------------------------------
// K1: x f32 [b][c][hw] -> Xbf bf16 [b][c][hw] AND XbfT bf16 [b][hw][c].
// Tile 64c x 128n. LDS row-major (c-major) with granule XOR swizzle;
// phase-1: b128 LDS writes + 16B Xbf stores; phase-2: short2 reads (2-way,
// free) + 16B stores where 8 lanes cover one contiguous 128B XbfT row.
// grid: dim3(32, 8, 16), 256 threads.
__global__ __launch_bounds__(256) void k_convert(const float* __restrict__ x,
                                                 short* __restrict__ Xbf,
                                                 short* __restrict__ XbfT) {
  __shared__ short T2[64 * 144];
  const int n0 = blockIdx.x * 128, c0 = blockIdx.y * 64, b = blockIdx.z;
  const int t = threadIdx.x;
  const int i = t >> 2;            // c within tile, 0..63
  const int jc = t & 3;
  const float* xrow = x + ((size_t)(b * C_ + c0 + i)) * HW_ + n0;
  short* yrow = Xbf + ((size_t)(b * C_ + c0 + i)) * HW_ + n0;
  const int gx = i >> 3;           // granule swizzle key
#pragma unroll
  for (int l = 0; l < 4; ++l) {
    const int n = jc * 8 + l * 32;
    const float4 v0 = *(const float4*)(xrow + n);
    const float4 v1 = *(const float4*)(xrow + n + 4);
    bf16x8 o;
    o[0] = f2bf(v0.x); o[1] = f2bf(v0.y); o[2] = f2bf(v0.z); o[3] = f2bf(v0.w);
    o[4] = f2bf(v1.x); o[5] = f2bf(v1.y); o[6] = f2bf(v1.z); o[7] = f2bf(v1.w);
    *(bf16x8*)(yrow + n) = o;
    *(bf16x8*)&T2[i * 144 + ((((n >> 3) ^ gx) << 3))] = o;
  }
  __syncthreads();
  const int cb = (t & 7) * 8;      // c chunk base, 0..56
  const int r0 = (t >> 3) * 2;     // even n row, 0..62
#pragma unroll
  for (int p = 0; p < 2; ++p) {
    const int r = r0 + p * 64;
    bf16x8 oa, ob;
#pragma unroll
    for (int e = 0; e < 8; ++e) {
      const int c = cb + e;
      const int idx = c * 144 + (((((r >> 3) ^ (c >> 3))) << 3) | (r & 7));
      const short2 pr = *(const short2*)&T2[idx];
      oa[e] = pr.x; ob[e] = pr.y;
    }
    short* orow = XbfT + ((size_t)b * HW_ + n0 + r) * C_ + c0 + cb;
    *(bf16x8*)(orow)      = oa;
    *(bf16x8*)(orow + C_) = ob;
  }
}

// ---------------------------------------------------------------------------
// K1b: conv_w f32 [256][512] -> Wbf bf16 [256][512].
__global__ __launch_bounds__(256) void k_wconv(const float* __restrict__ W,
                                               short* __restrict__ Wbf) {
  const int q = blockIdx.x, t = threadIdx.x;
  const float2 v = ((const float2*)(W + (size_t)q * C_))[t];
  short2 o; o.x = f2bf(v.x); o.y = f2bf(v.y);
  ((short2*)(Wbf + (size_t)q * C_))[t] = o;
}

// ---------------------------------------------------------------------------
// Shared NT-GEMM 128x128 mainloop, double-buffered LDS with prefetch
// (T3-minimum 2-phase: STAGE(next) || ds_read+MFMA(cur), one vmcnt+barrier
// per K-step). As/Bs are 2 x 4096-short buffers.
template<int KITER, int LDK>
__device__ __forceinline__ void nt_loop(const short* __restrict__ Ab,
                                        const short* __restrict__ Bb,
                                        short* As, short* Bs, int t,
                                        f32x4 (&acc)[4][4]) {
  const int lane = t & 63, w = t >> 6;
  const int wr = w >> 1, wc = w & 1;
  const int fr = lane & 15, fk = (lane >> 4) * 8;
  const int row_st = t >> 2, k_st = (t & 3) * 8;

#define STAGE_(buf, kk)                                                         \
  {                                                                             \
    const int k0_ = (kk) * 32 + k_st;                                           \
    gload_lds16(Ab + (size_t)row_st * LDK + k0_, As + (buf) * 4096 + t * 8);    \
    gload_lds16(Ab + (size_t)(row_st + 64) * LDK + k0_,                         \
                As + (buf) * 4096 + 2048 + t * 8);                              \
    gload_lds16(Bb + (size_t)row_st * LDK + k0_, Bs + (buf) * 4096 + t * 8);    \
    gload_lds16(Bb + (size_t)(row_st + 64) * LDK + k0_,                         \
                Bs + (buf) * 4096 + 2048 + t * 8);                              \
  }

  STAGE_(0, 0);
  asm volatile("s_waitcnt vmcnt(0)" ::: "memory");
  __builtin_amdgcn_s_barrier();
  int cur = 0;
  for (int kk = 0; kk < KITER; ++kk) {
    if (kk + 1 < KITER) STAGE_(cur ^ 1, kk + 1);
    const short* Ac = As + cur * 4096;
    const short* Bc = Bs + cur * 4096;
    bf16x8 a[4], bv[4];
#pragma unroll
    for (int m = 0; m < 4; ++m)
      a[m] = *(const bf16x8*)&Ac[(wr * 64 + m * 16 + fr) * 32 + fk];
#pragma unroll
    for (int n = 0; n < 4; ++n)
      bv[n] = *(const bf16x8*)&Bc[(wc * 64 + n * 16 + fr) * 32 + fk];
#pragma unroll
    for (int m = 0; m < 4; ++m)
#pragma unroll
      for (int n = 0; n < 4; ++n)
        acc[m][n] = __builtin_amdgcn_mfma_f32_16x16x32_bf16(a[m], bv[n], acc[m][n], 0, 0, 0);
    asm volatile("s_waitcnt vmcnt(0)" ::: "memory");
    __builtin_amdgcn_s_barrier();
    cur ^= 1;
  }
#undef STAGE_
}

// ---------------------------------------------------------------------------
// K2: Q[b][q][n] = sum_c W[q][c]*XbfT[b][n][c] + conv_b[q]  (bf16 out).
// grid: dim3(64, 16): x = nt*2+mt, y = b. 256 threads.
__global__ __launch_bounds__(256, 2) void k_q(const short* __restrict__ Wbf,
                                              const short* __restrict__ XbfT,
                                              const float* __restrict__ convb,
                                              short* __restrict__ Qbf) {
  __shared__ short As[2 * 4096];
  __shared__ short Bs[2 * 4096];
  const int t = threadIdx.x;
  const int mt = blockIdx.x & 1, nt = blockIdx.x >> 1, b = blockIdx.y;
  const short* Ab = Wbf + (size_t)(mt * 128) * C_;
  const short* Bb = XbfT + ((size_t)b * HW_ + nt * 128) * C_;
  f32x4 acc[4][4] = {};
  nt_loop<16, C_>(Ab, Bb, As, Bs, t, acc);
  const int lane = t & 63, w = t >> 6;
  const int wr = w >> 1, wc = w & 1;
  const int q_base = mt * 128 + wr * 64;
  const int n_base = nt * 128 + wc * 64;
#pragma unroll
  for (int m = 0; m < 4; ++m)
#pragma unroll
    for (int n = 0; n < 4; ++n) {
      const int q = q_base + m * 16 + (lane >> 4) * 4;
      const int nn = n_base + n * 16 + (lane & 15);
#pragma unroll
      for (int r = 0; r < 4; ++r)
        Qbf[((size_t)b * C1_ + q + r) * HW_ + nn] = f2bf(acc[m][n][r] + convb[q + r]);
    }
}

// ---------------------------------------------------------------------------
// K3: Ep[ks][b][q][c] = sum_{hw chunk ks} Q[b][q][hw]*X[b][c][hw] (bf16).
// grid: dim3(16, 8, NKS): x=b, y=ct*2+qt, z=ks. 256 threads.
template<int KITER>
__global__ __launch_bounds__(256, 2) void k_e(const short* __restrict__ Qbf,
                                              const short* __restrict__ Xbf,
                                              short* __restrict__ Ep) {
  __shared__ short As[2 * 4096];
  __shared__ short Bs[2 * 4096];
  const int t = threadIdx.x;
  const int b = blockIdx.x;
  const int qt = blockIdx.y & 1, ct = blockIdx.y >> 1;
  const int ks = blockIdx.z;
  const short* Ab = Qbf + ((size_t)b * C1_ + qt * 128) * HW_ + (size_t)ks * (KITER * 32);
  const short* Bb = Xbf + ((size_t)b * C_ + ct * 128) * HW_ + (size_t)ks * (KITER * 32);
  f32x4 acc[4][4] = {};
  nt_loop<KITER, HW_>(Ab, Bb, As, Bs, t, acc);
  const int lane = t & 63, w = t >> 6;
  const int wr = w >> 1, wc = w & 1;
  const int q_base = qt * 128 + wr * 64;
  const int c_base = ct * 128 + wc * 64;
#pragma unroll
  for (int m = 0; m < 4; ++m)
#pragma unroll
    for (int n = 0; n < 4; ++n) {
      const int q = q_base + m * 16 + (lane >> 4) * 4;
      const int c = c_base + n * 16 + (lane & 15);
#pragma unroll
      for (int r = 0; r < 4; ++r)
        Ep[(((size_t)ks * B_ + b) * C1_ + q + r) * C_ + c] = f2bf(acc[m][n][r]);
    }
}

// ---------------------------------------------------------------------------
// K4: per (b,q) row: E = (sum_ks Ep)/64; A = softmax(E); Mb = gamma*A + W[q].
// grid: 4096 blocks (b*256+q), 128 threads (4 consecutive c each).
template<int NKS>
__global__ __launch_bounds__(128) void k_softmax(const short* __restrict__ Ep,
                                                 const float* __restrict__ W,
                                                 const float* __restrict__ gamma,
                                                 short* __restrict__ Mb) {
  const int bq = blockIdx.x;
  const int b = bq >> 8, q = bq & 255;
  const int t = threadIdx.x;
  const float g = gamma[0];
  float e[4] = {0.f, 0.f, 0.f, 0.f};
#pragma unroll
  for (int ks = 0; ks < NKS; ++ks) {
    const short4 v = *(const short4*)&Ep[(((size_t)ks * B_ + b) * C1_ + q) * C_ + t * 4];
    e[0] += bf2f(v.x); e[1] += bf2f(v.y); e[2] += bf2f(v.z); e[3] += bf2f(v.w);
  }
#pragma unroll
  for (int d = 0; d < 4; ++d) e[d] *= 0.015625f;
  float mx = fmaxf(fmaxf(e[0], e[1]), fmaxf(e[2], e[3]));
#pragma unroll
  for (int off = 1; off < 64; off <<= 1) mx = fmaxf(mx, __shfl_xor(mx, off));
  __shared__ float red[2];
  if ((t & 63) == 0) red[t >> 6] = mx;
  __syncthreads();
  mx = fmaxf(red[0], red[1]);
  const float e0 = __expf(e[0] - mx), e1 = __expf(e[1] - mx);
  const float e2 = __expf(e[2] - mx), e3 = __expf(e[3] - mx);
  float sum = (e0 + e1) + (e2 + e3);
#pragma unroll
  for (int off = 1; off < 64; off <<= 1) sum += __shfl_xor(sum, off);
  __shared__ float red2[2];
  if ((t & 63) == 0) red2[t >> 6] = sum;
  __syncthreads();
  const float inv = 1.0f / (red2[0] + red2[1]);
  const float4 wv = ((const float4*)(W + (size_t)q * C_))[t];
  short4 o;
  o.x = f2bf(g * e0 * inv + wv.x);
  o.y = f2bf(g * e1 * inv + wv.y);
  o.z = f2bf(g * e2 * inv + wv.z);
  o.w = f2bf(g * e3 * inv + wv.w);
  ((short4*)(Mb + (size_t)bq * C_))[t] = o;
}

// ---------------------------------------------------------------------------
// K5: out[b][o][n] = sum_c Mb[b][o][c]*XbfT[b][n][c] + conv_b[o]  (f32).
// grid: dim3(64, 16), 256 threads.
__global__ __launch_bounds__(256, 2) void k_out(const short* __restrict__ Mb,
                                                const short* __restrict__ XbfT,
                                                const float* __restrict__ convb,
                                                float* __restrict__ out) {
  __shared__ short As[2 * 4096];
  __shared__ short Bs[2 * 4096];
  const int t = threadIdx.x;
  const int mt = blockIdx.x & 1, nt = blockIdx.x >> 1, b = blockIdx.y;
  const short* Ab = Mb + ((size_t)b * C1_ + mt * 128) * C_;
  const short* Bb = XbfT + ((size_t)b * HW_ + nt * 128) * C_;
  f32x4 acc[4][4] = {};
  nt_loop<16, C_>(Ab, Bb, As, Bs, t, acc);
  const int lane = t & 63, w = t >> 6;
  const int wr = w >> 1, wc = w & 1;
  const int o_base = mt * 128 + wr * 64;
  const int n_base = nt * 128 + wc * 64;
#pragma unroll
  for (int m = 0; m < 4; ++m)
#pragma unroll
    for (int n = 0; n < 4; ++n) {
      const int oo = o_base + m * 16 + (lane >> 4) * 4;
      const int nn = n_base + n * 16 + (lane & 15);
#pragma unroll
      for (int r = 0; r < 4; ++r)
        out[((size_t)b * C1_ + oo + r) * HW_ + nn] = acc[m][n][r] + convb[oo + r];
    }
}

// ---------------------------------------------------------------------------
extern "C" void kernel_launch(void* const* d_in, const int* in_sizes, int n_in,
                              void* d_out, int out_size, void* d_ws, size_t ws_size,
                              hipStream_t stream) {
  const float* x      = (const float*)d_in[0];
  const float* conv_w = (const float*)d_in[1];
  const float* conv_b = (const float*)d_in[2];
  const float* gamma  = (const float*)d_in[3];
  float* out = (float*)d_out;

  char* ws = (char*)d_ws;
  short* Xbf  = (short*)(ws);                 //  67,108,864 B : bf16 [16][512][4096]
  short* XbfT = (short*)(ws + 67108864);      //  67,108,864 B : bf16 [16][4096][512]
  short* Qbf  = (short*)(ws + 134217728);     //  33,554,432 B : bf16 [16][256][4096]
  short* Mb   = (short*)(ws + 134217728);     //  (aliases Qbf; Qbf dead by then)
  short* Ep   = (short*)(ws + 167772160);     //  up to 33,554,432 B (8 splits)
  const bool big = ws_size >= 201588736ull;   //  split-K 8 if Ep x8 + Wbf fit
  short* Wbf  = (short*)(ws + (big ? 201326592u : 184549376u));

  k_convert<<<dim3(32, 8, 16), 256, 0, stream>>>(x, Xbf, XbfT);
  k_wconv<<<256, 256, 0, stream>>>(conv_w, Wbf);
  k_q<<<dim3(64, 16), 256, 0, stream>>>(Wbf, XbfT, conv_b, Qbf);
  if (big) {
    k_e<16><<<dim3(16, 8, 8), 256, 0, stream>>>(Qbf, Xbf, Ep);
    k_softmax<8><<<4096, 128, 0, stream>>>(Ep, conv_w, gamma, Mb);
  } else {
    k_e<32><<<dim3(16, 8, 4), 256, 0, stream>>>(Qbf, Xbf, Ep);
    k_softmax<4><<<4096, 128, 0, stream>>>(Ep, conv_w, gamma, Mb);
  }
  k_out<<<dim3(64, 16), 256, 0, stream>>>(Mb, XbfT, conv_b, out);
}